// Round 1
// baseline (297.374 us; speedup 1.0000x reference)
//
#include <hip/hip_runtime.h>
#include <hip/hip_bf16.h>

#define N_SEND 12288
#define N_REC  49152
#define NEDGE  196608
#define AREC   16      // receivers per aggregate block
#define AECAP  256     // edge chunk capacity in aggregate

typedef __attribute__((ext_vector_type(8)))  short short8;
typedef __attribute__((ext_vector_type(4)))  short shortx4;
typedef __attribute__((ext_vector_type(4)))  float floatx4;
typedef __attribute__((ext_vector_type(16))) float floatx16;
typedef __attribute__((ext_vector_type(4)))  unsigned int uintx4;

__device__ inline short f2bs(float f) {
    __hip_bfloat16 h = __float2bfloat16(f);
    return *reinterpret_cast<short*>(&h);
}
// jax.nn.gelu default approximate=True (tanh form)
__device__ inline float gelu_tanh(float x) {
    const float k0 = 0.7978845608028654f;
    float u = k0 * (x + 0.044715f * x * x * x);
    float e = __expf(2.0f * u);
    float t = 1.0f - 2.0f / (e + 1.0f);
    return 0.5f * x * (1.0f + t);
}

__device__ inline void gload_lds16(const short* g, short* l) {
    __builtin_amdgcn_global_load_lds(
        (const __attribute__((address_space(1))) unsigned int*)g,
        (__attribute__((address_space(3))) unsigned int*)l, 16, 0, 0);
}

// ---- prep: BT1[n][0:256]=Wl1lo^T, BT1[n][256:512]=(We2@Wl1hi)^T, WT2=Wl2^T, cvec=be2@Wl1hi
__global__ void prep_kernel(const float* __restrict__ We2, const float* __restrict__ be2,
                            const float* __restrict__ Wl1, const float* __restrict__ Wl2,
                            short* __restrict__ BT1, short* __restrict__ WT2,
                            float* __restrict__ cvec) {
    int i = blockIdx.x;
    int n = threadIdx.x;
    if (i < 256) {
        float acc = 0.f;
        for (int j = 0; j < 256; ++j)
            acc += We2[i * 256 + j] * Wl1[(256 + j) * 256 + n];
        BT1[n * 512 + i]       = f2bs(Wl1[i * 256 + n]);   // k<256: Wl1lo
        BT1[n * 512 + 256 + i] = f2bs(acc);                // k>=256: M = We2@Wl1hi
        WT2[n * 256 + i]       = f2bs(Wl2[i * 256 + n]);
    } else {
        float acc = 0.f;
        for (int j = 0; j < 256; ++j)
            acc += be2[j] * Wl1[(256 + j) * 256 + n];
        cvec[n] = acc;
    }
}

// ---- xcast: Xb = bf16(X), [2][N_SEND][256]
__global__ void xcast_kernel(const float* __restrict__ X, short* __restrict__ Xb) {
    int i = (blockIdx.x * 256 + threadIdx.x) * 8;
    floatx4 v0 = *(const floatx4*)(X + i);
    floatx4 v1 = *(const floatx4*)(X + i + 4);
    short8 p;
#pragma unroll
    for (int j = 0; j < 4; ++j) { p[j] = f2bs(v0[j]); p[j + 4] = f2bs(v1[j]); }
    *(short8*)(Xb + i) = p;
}

// ---- bounds: bnd[r] = lower_bound(idx_rec, r), r in [0, N_REC]
__global__ void bounds_kernel(const int* __restrict__ idx_rec, int* __restrict__ bnd) {
    int r = blockIdx.x * 256 + threadIdx.x;
    if (r > N_REC) return;
    int lo = 0, hi = NEDGE;
    while (lo < hi) { int mid = (lo + hi) >> 1; if (idx_rec[mid] < r) lo = mid + 1; else hi = mid; }
    bnd[r] = lo;
}

// ==== aggregate: 16 receivers/block, 512 threads, ~29 KB LDS -> 3-4 blocks/CU.
// Computes Xagg (2 batches) and Hagg = sum gelu(ea@We1+be1) per receiver, writes
// fragment-major tile images to global:
//   AGX[ablk][kg=32][r32=32][8]  (r32 = b*16 + rl_local), 16 KB / block
//   AGH[ablk][kg=32][rl'=16][8],                           8 KB / block
__global__ __launch_bounds__(512, 6)
void aggregate(const int* __restrict__ idx_send, const int* __restrict__ bnd,
               const float* __restrict__ EA, const float* __restrict__ We1,
               const float* __restrict__ be1, const short* __restrict__ Xb,
               short* __restrict__ AGX, short* __restrict__ AGH) {
    __shared__ __attribute__((aligned(16))) short XTs[32 * 32 * 8];  // 16 KB
    __shared__ __attribute__((aligned(16))) short HTs[32 * 16 * 8];  //  8 KB
    __shared__ int   sb[AREC + 1];
    __shared__ int   s_idx[AECAP];
    __shared__ __attribute__((aligned(16))) float s_ea[AECAP * 4];

    int t = threadIdx.x;
    int r0 = blockIdx.x * AREC;
    if (t <= AREC) sb[t] = bnd[r0 + t];
    __syncthreads();
    int e0 = sb[0], eN = sb[AREC];

    int cg = t & 31;          // 8-col group
    int b  = (t >> 5) & 1;    // batch
    int rh = t >> 6;          // wave id: handles receivers rh*2, rh*2+1
    int c8 = cg * 8;
    int hc = c8 + 4 * b;

    floatx4 w0 = *(const floatx4*)(We1 + hc);
    floatx4 w1 = *(const floatx4*)(We1 + 256 + hc);
    floatx4 w2 = *(const floatx4*)(We1 + 512 + hc);
    floatx4 w3 = *(const floatx4*)(We1 + 768 + hc);
    floatx4 bb = *(const floatx4*)(be1 + hc);
    const short* xb_t = Xb + (size_t)b * N_SEND * 256 + c8;

    float xacc[2][8];
    float hacc[2][4];
#pragma unroll
    for (int r = 0; r < 2; ++r) {
#pragma unroll
        for (int c = 0; c < 8; ++c) xacc[r][c] = 0.f;
#pragma unroll
        for (int c = 0; c < 4; ++c) hacc[r][c] = 0.f;
    }

    for (int base = e0; base < eN; base += AECAP) {
        int cnt = min(AECAP, eN - base);
        __syncthreads();
        for (int i = t; i < cnt; i += 512) {
            s_idx[i] = idx_send[base + i];
            *(floatx4*)(s_ea + 4 * i) = *(const floatx4*)(EA + (size_t)(base + i) * 4);
        }
        __syncthreads();
#pragma unroll
        for (int r = 0; r < 2; ++r) {
            int rl = rh * 2 + r;
            int es = max(sb[rl], base);
            int ee = min(sb[rl + 1], base + cnt);
            for (int e = es; e < ee; ++e) {
                int li = e - base;
                int s = s_idx[li];
                uintx4 xv = *(const uintx4*)(xb_t + (size_t)s * 256);
                floatx4 a = *(const floatx4*)(s_ea + 4 * li);
#pragma unroll
                for (int dw = 0; dw < 4; ++dw) {
                    xacc[r][2 * dw]     += __builtin_bit_cast(float, xv[dw] << 16);
                    xacc[r][2 * dw + 1] += __builtin_bit_cast(float, xv[dw] & 0xffff0000u);
                }
#pragma unroll
                for (int j = 0; j < 4; ++j) {
                    float u = a[0] * w0[j] + a[1] * w1[j] + a[2] * w2[j] + a[3] * w3[j] + bb[j];
                    hacc[r][j] += gelu_tanh(u);
                }
            }
        }
    }
    // write fragment-major tiles to LDS (staging for coalesced global store)
#pragma unroll
    for (int r = 0; r < 2; ++r) {
        int rl = rh * 2 + r;
        short8 xp;
#pragma unroll
        for (int c = 0; c < 8; ++c) xp[c] = f2bs(xacc[r][c]);
        *(short8*)(XTs + (cg * 32 + b * 16 + rl) * 8) = xp;
        shortx4 hp;
#pragma unroll
        for (int c = 0; c < 4; ++c) hp[c] = f2bs(hacc[r][c]);
        *(shortx4*)(HTs + (cg * 16 + rl) * 8 + 4 * b) = hp;
    }
    __syncthreads();
    // coalesced copy LDS -> global tile images
    {
        const uintx4* xs = (const uintx4*)XTs;
        uintx4* xd = (uintx4*)(AGX + (size_t)blockIdx.x * (32 * 32 * 8));
        xd[t]       = xs[t];
        xd[t + 512] = xs[t + 512];
        const uintx4* hs = (const uintx4*)HTs;
        uintx4* hd = (uintx4*)(AGH + (size_t)blockIdx.x * (32 * 16 * 8));
        hd[t] = hs[t];
    }
}

// ==== gemm: 64 receivers/block (= 4 aggregate blocks), 512 threads, 8 waves.
// Stage precomputed tiles linearly via global_load_lds, then:
//   GEMM1 K=512 ([X|H] @ BT1^T) + gelu -> T in LDS; GEMM2 K=256 (T @ WT2^T) -> OUT.
// Row decode: row' = rt*32+m  ->  a'=rt, batch=(m>>4)&1, receiver=rt*16+(m&15).
__global__ __launch_bounds__(512, 2)
void gemm(const int* __restrict__ bnd, const short* __restrict__ AGX,
          const short* __restrict__ AGH, const short* __restrict__ BT1,
          const short* __restrict__ WT2, const float* __restrict__ cvec,
          const float* __restrict__ bl1, const float* __restrict__ bl2,
          float* __restrict__ OUT) {
    __shared__ __attribute__((aligned(16))) short XT[4 * 32 * 32 * 8];  // 64 KB; reused for T [f2][row'][8]
    __shared__ __attribute__((aligned(16))) short HT[4 * 32 * 16 * 8];  // 32 KB
    __shared__ int sb[65];

    int t = threadIdx.x;
    int blk = blockIdx.x;
    int r0 = blk * 64;
    if (t < 65) sb[t] = bnd[r0 + t];

    // linear stage: XT 65536 B = 4096 x16B chunks, HT 32768 B = 2048 chunks
    {
        const short* sx = AGX + (size_t)blk * (4 * 32 * 32 * 8);
        const short* sh = AGH + (size_t)blk * (4 * 32 * 16 * 8);
#pragma unroll
        for (int k = 0; k < 8; ++k) {
            int c = t + k * 512;
            gload_lds16(sx + c * 8, XT + c * 8);
        }
#pragma unroll
        for (int k = 0; k < 4; ++k) {
            int c = t + k * 512;
            gload_lds16(sh + c * 8, HT + c * 8);
        }
    }
    __syncthreads();

    // ---------------- GEMM1 (K=512) ----------------
    int w = t >> 6, lane = t & 63;
    int m = lane & 31, q = lane >> 5;
    int wcol = w * 32;
    floatx16 acc[4];
#pragma unroll
    for (int i = 0; i < 4; ++i)
#pragma unroll
        for (int j = 0; j < 16; ++j) acc[i][j] = 0.f;

    const short* Bp1 = BT1 + (size_t)(wcol + m) * 512 + q * 8;
    short8 bfA[4], bfB[4];
#pragma unroll
    for (int kk = 0; kk < 4; ++kk) bfA[kk] = *(const short8*)(Bp1 + kk * 16);

#pragma unroll
    for (int ci = 0; ci < 8; ++ci) {
        int kc = ci * 64;
        const short8* bc = (ci & 1) ? bfB : bfA;
        short8*       bn = (ci & 1) ? bfA : bfB;
        if (ci < 7) {
#pragma unroll
            for (int kk = 0; kk < 4; ++kk)
                bn[kk] = *(const short8*)(Bp1 + kc + 64 + kk * 16);
        }
#pragma unroll
        for (int kk = 0; kk < 4; ++kk) {
            int f = (kc >> 3) + 2 * kk + q;
#pragma unroll
            for (int rt = 0; rt < 4; ++rt) {
                const short* ap = (ci < 4)
                    ? (XT + rt * 8192 + f * 256 + m * 8)
                    : (HT + rt * 4096 + (f - 32) * 128 + (m & 15) * 8);
                short8 a = *(const short8*)ap;
                acc[rt] = __builtin_amdgcn_mfma_f32_32x32x16_bf16(bc[kk], a, acc[rt], 0, 0, 0);
            }
        }
    }
    __syncthreads();   // all waves done reading XT/HT

    // ---- epilogue1: gelu(acc + cnt*cvec + bl1) -> T (into XT, fragment-major) ----
#pragma unroll
    for (int rt = 0; rt < 4; ++rt) {
        int row = rt * 32 + m;
        int rl = rt * 16 + (m & 15);
        float cntv = (float)(sb[rl + 1] - sb[rl]);
#pragma unroll
        for (int qd = 0; qd < 4; ++qd) {
            int c0 = wcol + qd * 8 + q * 4;
            floatx4 cv  = *(const floatx4*)(cvec + c0);
            floatx4 b1v = *(const floatx4*)(bl1 + c0);
            shortx4 pk;
#pragma unroll
            for (int j = 0; j < 4; ++j)
                pk[j] = f2bs(gelu_tanh(acc[rt][qd * 4 + j] + cntv * cv[j] + b1v[j]));
            *(shortx4*)(XT + ((w * 4 + qd) * 128 + row) * 8 + q * 4) = pk;
        }
#pragma unroll
        for (int j = 0; j < 16; ++j) acc[rt][j] = 0.f;
    }
    __syncthreads();

    // ---------------- GEMM2 (K=256): T @ WT2^T ----------------
    const short* Bp2 = WT2 + (size_t)(wcol + m) * 256 + q * 8;
#pragma unroll
    for (int kk = 0; kk < 4; ++kk) bfA[kk] = *(const short8*)(Bp2 + kk * 16);

#pragma unroll
    for (int ci = 0; ci < 4; ++ci) {
        int kc = ci * 64;
        const short8* bc = (ci & 1) ? bfB : bfA;
        short8*       bn = (ci & 1) ? bfA : bfB;
        if (ci < 3) {
#pragma unroll
            for (int kk = 0; kk < 4; ++kk)
                bn[kk] = *(const short8*)(Bp2 + kc + 64 + kk * 16);
        }
#pragma unroll
        for (int kk = 0; kk < 4; ++kk) {
            int f2 = (kc >> 3) + 2 * kk + q;
#pragma unroll
            for (int rt = 0; rt < 4; ++rt) {
                short8 a = *(const short8*)(XT + (f2 * 128 + rt * 32 + m) * 8);
                acc[rt] = __builtin_amdgcn_mfma_f32_32x32x16_bf16(bc[kk], a, acc[rt], 0, 0, 0);
            }
        }
    }

    // ---- epilogue2: + bl2 -> OUT ----
#pragma unroll
    for (int rt = 0; rt < 4; ++rt) {
        int batch = (m >> 4) & 1;
        int rl = rt * 16 + (m & 15);
        size_t obase = ((size_t)batch * N_REC + r0 + rl) * 256;
#pragma unroll
        for (int qd = 0; qd < 4; ++qd) {
            int c0 = wcol + qd * 8 + q * 4;
            floatx4 bv = *(const floatx4*)(bl2 + c0);
            floatx4 o;
#pragma unroll
            for (int j = 0; j < 4; ++j)
                o[j] = acc[rt][qd * 4 + j] + bv[j];
            *(floatx4*)(OUT + obase + c0) = o;
        }
    }
}

extern "C" void kernel_launch(void* const* d_in, const int* in_sizes, int n_in,
                              void* d_out, int out_size, void* d_ws, size_t ws_size,
                              hipStream_t stream) {
    const float* x        = (const float*)d_in[0];
    const float* ea       = (const float*)d_in[1];
    const int*   idx_send = (const int*)d_in[2];
    const int*   idx_rec  = (const int*)d_in[3];
    const float* We1      = (const float*)d_in[4];
    const float* be1      = (const float*)d_in[5];
    const float* We2      = (const float*)d_in[6];
    const float* be2      = (const float*)d_in[7];
    const float* Wl1      = (const float*)d_in[8];
    const float* bl1      = (const float*)d_in[9];
    const float* Wl2      = (const float*)d_in[10];
    const float* bl2      = (const float*)d_in[11];
    float* out = (float*)d_out;
    char*  ws  = (char*)d_ws;

    short* BT1  = (short*)(ws + 0);           // 262144 B
    short* WT2  = (short*)(ws + 262144);      // 131072 B
    float* cvec = (float*)(ws + 393216);      // 1024 B
    int*   bnd  = (int*)  (ws + 397312);      // 196612 B
    short* Xb   = (short*)(ws + 1048576);     // 12.58 MB
    short* AGX  = (short*)(ws + 13631488);    // 3072 * 16384 B = 50.33 MB
    short* AGH  = (short*)(ws + 63963136);    // 3072 *  8192 B = 25.17 MB  (total ~89.1 MB)

    prep_kernel<<<257, 256, 0, stream>>>(We2, be2, Wl1, Wl2, BT1, WT2, cvec);
    xcast_kernel<<<(2 * N_SEND * 256) / (256 * 8), 256, 0, stream>>>(x, Xb);
    bounds_kernel<<<(N_REC + 1 + 255) / 256, 256, 0, stream>>>(idx_rec, bnd);
    aggregate<<<N_REC / AREC, 512, 0, stream>>>(idx_send, bnd, ea, We1, be1, Xb, AGX, AGH);
    gemm<<<N_REC / 64, 512, 0, stream>>>(bnd, AGX, AGH, BT1, WT2, cvec, bl1, bl2, out);
}